// Round 1
// baseline (558.291 us; speedup 1.0000x reference)
//
#include <hip/hip_runtime.h>
#include <stdint.h>

#define CIN 64
#define COUT 128
#define TILE_ROWS 64
#define BLOCK 256
#define WT_STRIDE 136   // 128 + 8 pad, in ushorts (272 B rows -> bank rotate by 4)
#define A_STRIDE 136

typedef __attribute__((ext_vector_type(8))) __bf16 bf16x8;
typedef __attribute__((ext_vector_type(8))) unsigned short ushort8;
typedef __attribute__((ext_vector_type(4))) float f32x4;

__device__ __forceinline__ unsigned short f2bf(float f) {
    // round-to-nearest-even fp32 -> bf16
    uint32_t u = __float_as_uint(f);
    u = (u + 0x7FFFu + ((u >> 16) & 1u)) >> 16;
    return (unsigned short)u;
}

// Build inverse map: for each input row i, record i+1 at inv[kz][out_ids[i]].
// At most one input per (output, tap) pair -> plain stores, no atomics needed.
__global__ void scatter_inv_kernel(const int* __restrict__ kz,
                                   const int* __restrict__ oid,
                                   int* __restrict__ inv0,
                                   int* __restrict__ inv1,
                                   int n) {
    int i = blockIdx.x * blockDim.x + threadIdx.x;
    if (i < n) {
        int o = oid[i];
        if (kz[i] == 0) inv0[o] = i + 1;
        else            inv1[o] = i + 1;
    }
}

__launch_bounds__(BLOCK)
__global__ void spconv_bn_relu_kernel(const float* __restrict__ feat,
                                      const float* __restrict__ W,
                                      const float* __restrict__ gamma,
                                      const float* __restrict__ beta,
                                      const float* __restrict__ rmean,
                                      const float* __restrict__ rvar,
                                      const int* __restrict__ inv0,
                                      const int* __restrict__ inv1,
                                      const int* __restrict__ n_out_p,
                                      float* __restrict__ out,
                                      int N, int num_tiles) {
    __shared__ unsigned short lds_wT[COUT * WT_STRIDE];      // 34816 B, WcatT[n][k] bf16
    __shared__ unsigned short lds_a[TILE_ROWS * A_STRIDE];   // 17408 B, A[r][k] bf16
    __shared__ float lds_scale[COUT];
    __shared__ float lds_bias[COUT];

    const int tid = threadIdx.x;
    const int nout = *n_out_p;

    // ---- phase 0 (once per block): Wcat -> LDS, transposed, bf16 ----
    // W global layout: [tap][cin][cout] flat = (tap*64+cin)*128 + cout = k*128 + n
    const float4* W4 = (const float4*)W;
    #pragma unroll
    for (int u = 0; u < 16; ++u) {
        int flat4 = u * BLOCK + tid;   // 0..4095 float4s
        int n4 = flat4 & 31;           // float4 index within a 128-cout row
        int k  = flat4 >> 5;           // 0..127 = tap*64+cin
        float4 v = W4[flat4];
        int nb = n4 * 4;
        lds_wT[(nb + 0) * WT_STRIDE + k] = f2bf(v.x);
        lds_wT[(nb + 1) * WT_STRIDE + k] = f2bf(v.y);
        lds_wT[(nb + 2) * WT_STRIDE + k] = f2bf(v.z);
        lds_wT[(nb + 3) * WT_STRIDE + k] = f2bf(v.w);
    }
    if (tid < COUT) {
        float s = gamma[tid] * rsqrtf(rvar[tid] + 1e-5f);
        lds_scale[tid] = s;
        lds_bias[tid]  = fmaf(-rmean[tid], s, beta[tid]);
    }
    __syncthreads();

    const float4* feat4 = (const float4*)feat;
    const int wave = tid >> 6;
    const int lane = tid & 63;
    const int lrow = lane & 15;
    const int quad = lane >> 4;

    for (int tile = blockIdx.x; tile < num_tiles; tile += gridDim.x) {
        const int tile_base = tile * TILE_ROWS;

        // ---- stage A tile: 64 rows x 128 k (bf16), gathered via inv maps ----
        // 64 rows * 2 taps * 16 float4-chunks = 2048 loads, 8 per thread
        #pragma unroll
        for (int u = 0; u < 8; ++u) {
            int flat  = u * BLOCK + tid;  // 0..2047
            int r     = flat >> 5;
            int rem   = flat & 31;
            int tap   = rem >> 4;
            int chunk = rem & 15;
            int o = tile_base + r;
            int idx = 0;
            if (o < N) idx = tap ? inv1[o] : inv0[o];
            float4 v = make_float4(0.f, 0.f, 0.f, 0.f);
            if (idx > 0) v = feat4[(size_t)(idx - 1) * 16 + chunk];
            uint2 p;
            p.x = (uint32_t)f2bf(v.x) | ((uint32_t)f2bf(v.y) << 16);
            p.y = (uint32_t)f2bf(v.z) | ((uint32_t)f2bf(v.w) << 16);
            *(uint2*)&lds_a[r * A_STRIDE + tap * 64 + chunk * 4] = p;
        }
        __syncthreads();

        // ---- MFMA: each wave computes 16 rows x 128 cols ----
        const unsigned short* abase = &lds_a[(wave * 16 + lrow) * A_STRIDE + quad * 8];
        bf16x8 afrag[4];
        #pragma unroll
        for (int s = 0; s < 4; ++s)
            afrag[s] = __builtin_bit_cast(bf16x8, *(const ushort8*)(abase + s * 32));

        #pragma unroll
        for (int c = 0; c < 8; ++c) {
            const unsigned short* bbase = &lds_wT[(c * 16 + lrow) * WT_STRIDE + quad * 8];
            f32x4 acc = {0.f, 0.f, 0.f, 0.f};
            #pragma unroll
            for (int s = 0; s < 4; ++s) {
                bf16x8 bfrag = __builtin_bit_cast(bf16x8, *(const ushort8*)(bbase + s * 32));
                acc = __builtin_amdgcn_mfma_f32_16x16x32_bf16(afrag[s], bfrag, acc, 0, 0, 0);
            }
            // epilogue: BN (eval) + ReLU, zero rows >= n_out
            int col = c * 16 + lrow;
            float sc = lds_scale[col];
            float bi = lds_bias[col];
            int rbase = tile_base + wave * 16 + quad * 4;
            #pragma unroll
            for (int reg = 0; reg < 4; ++reg) {
                int o = rbase + reg;
                if (o < N) {
                    float v = 0.f;
                    if (o < nout) v = fmaxf(fmaf(acc[reg], sc, bi), 0.f);
                    out[(size_t)o * COUT + col] = v;
                }
            }
        }
        __syncthreads();   // protect lds_a before next tile's staging
    }
}

extern "C" void kernel_launch(void* const* d_in, const int* in_sizes, int n_in,
                              void* d_out, int out_size, void* d_ws, size_t ws_size,
                              hipStream_t stream) {
    const float* feat  = (const float*)d_in[0];
    const float* W     = (const float*)d_in[1];
    const float* gamma = (const float*)d_in[2];
    const float* beta  = (const float*)d_in[3];
    const float* rmean = (const float*)d_in[4];
    const float* rvar  = (const float*)d_in[5];
    const int*   kz    = (const int*)d_in[6];
    const int*   oid   = (const int*)d_in[7];
    const int*   noutp = (const int*)d_in[8];
    float* out = (float*)d_out;

    const int N = in_sizes[6];   // 600000

    int* inv0 = (int*)d_ws;
    int* inv1 = inv0 + N;

    // inv maps: 0 = no contributor (ws is re-poisoned each call, so always clear)
    hipMemsetAsync(d_ws, 0, (size_t)2 * N * sizeof(int), stream);

    int sb = (N + 255) / 256;
    scatter_inv_kernel<<<sb, 256, 0, stream>>>(kz, oid, inv0, inv1, N);

    int num_tiles = (N + TILE_ROWS - 1) / TILE_ROWS;   // 9375
    int grid = num_tiles < 1875 ? num_tiles : 1875;    // 5 tiles/block, amortize W load
    spconv_bn_relu_kernel<<<grid, BLOCK, 0, stream>>>(
        feat, W, gamma, beta, rmean, rvar, inv0, inv1, noutp, out, N, num_tiles);
}